// Round 6
// baseline (41977.142 us; speedup 1.0000x reference)
//
#include <hip/hip_runtime.h>
#include <stdint.h>
#include <stddef.h>

// DARTS RNN cell, MI355X. Round 8: L2-cached state exchange with
// acquire-invalidate barriers.
//
// Round-7 budget at 38us/step: VALU 7us, barriers ~6us, exposed latency
// ~4us -> ~20us unexplained. That term is LLC BANDWIDTH: sc0sc1 state
// loads bypass L1+L2, so each phase reads 128KB x 256 wgs = 32MB from the
// Infinity Cache (~220MB/step) - a 15-25us/step BW floor from 32x
// redundant reads per XCD.
//
// Fix: states are read with NORMAL cached loads (first wg per XCD fills
// L2, the rest hit L2; LLC traffic per phase drops 32x). Coherence is
// kept by (a) sc1 write-through STORES (unchanged - data is at LLC before
// the gen bump; no release/writeback needed), and (b) ONE agent-scope
// acquire fence (buffer_inv: L1+L2 invalidate) in grid_wait after gen is
// observed, before any state load. This is the acquire HALF of round-1's
// acq/rel scheme - without the buffer_wbl2 dirty-walk that made it slow.
//
// Carried: relaxed monotonic hierarchical barrier, depth-8 two-stage
// K-loop preload, own-column values in registers, x-part overlapped under
// the final barrier wait, nontemporal out stores.
//
// Partition: 256 wgs x 512 thr; wg owns 2 state columns; weights in LDS
// (80 KB). 5 grid barriers per timestep.

#define TT 1024
#define BB 64
#define HH 512
#define C2H 1024
#define NBLK 256
#define NTHR 512

#define NW_ENT 5120
#define W0_OFF 0
#define WS_OFF(m) (4096 + (m) * 2048)

#define RED_SLOTS 24

#define SCOPE __HIP_MEMORY_SCOPE_AGENT

// ---- state loads: NORMAL cached (L1+L2). Coherence via barrier inv. ----
__device__ __forceinline__ float4 ld_v4(const float* p) {
    return *(const float4*)p;
}

// ---- state stores: sc1 write-through (visible at LLC when vmcnt drains) ----
__device__ __forceinline__ void st_f1(float* p, float v) {
    union { float f; unsigned u; } c; c.f = v;
    __hip_atomic_store((unsigned*)p, c.u, __ATOMIC_RELAXED, SCOPE);
}

// ---- grid barrier: hierarchical, monotonic, relaxed RMWs ----
// bar layout (unsigned): leaf i at bar[16*i] (i<8), root at bar[128],
// gen at bar[144]. Counters never reset; (a&31)==31 / (r&7)==7 arm the
// next stage. 5*1024 barriers << 2^32/32, no overflow.
__device__ __forceinline__ unsigned grid_arrive(unsigned* bar) {
    __syncthreads();   // drains this wg's sc1 stores (vmcnt 0) in every wave
    unsigned g = 0;
    if (threadIdx.x == 0) {
        unsigned* leaf = bar + 16 * (blockIdx.x & 7);
        unsigned* root = bar + 128;
        unsigned* gen  = bar + 144;
        g = __hip_atomic_load(gen, __ATOMIC_RELAXED, SCOPE);
        unsigned a = __hip_atomic_fetch_add(leaf, 1u, __ATOMIC_RELAXED, SCOPE);
        if ((a & 31u) == 31u) {
            unsigned r = __hip_atomic_fetch_add(root, 1u, __ATOMIC_RELAXED, SCOPE);
            if ((r & 7u) == 7u) {
                __hip_atomic_fetch_add(gen, 1u, __ATOMIC_RELAXED, SCOPE);
            }
        }
    }
    return g;
}

__device__ __forceinline__ void grid_wait(unsigned* bar, unsigned g) {
    if (threadIdx.x == 0) {
        unsigned* gen = bar + 144;
        while (__hip_atomic_load(gen, __ATOMIC_RELAXED, SCOPE) == g) {
            __builtin_amdgcn_s_sleep(2);
        }
        // acquire: invalidate this CU's L1 and the XCD's L2 so the cached
        // state loads below observe the sc1 stores published before gen.
        __builtin_amdgcn_fence(__ATOMIC_ACQUIRE, "agent");
    }
    __syncthreads();
}

__device__ __forceinline__ void grid_barrier(unsigned* bar) {
    unsigned g = grid_arrive(bar);
    grid_wait(bar, g);
}

__device__ __forceinline__ float fsigmoid(float v) {
    return 1.f / (1.f + __expf(-v));
}

// act codes: 0=sigmoid 1=relu 2=tanh 3=identity
__device__ __forceinline__ float factivate(int a, float v) {
    if (a == 0) return fsigmoid(v);
    if (a == 1) return fmaxf(v, 0.f);
    if (a == 2) return tanhf(v);
    return v;
}

// 16 FMAs: acc[c][q] += v[q] * w[c]
__device__ __forceinline__ void fma16(float (&acc)[4][4], const float4 v, const float4 w) {
    acc[0][0] = fmaf(v.x, w.x, acc[0][0]);
    acc[0][1] = fmaf(v.y, w.x, acc[0][1]);
    acc[0][2] = fmaf(v.z, w.x, acc[0][2]);
    acc[0][3] = fmaf(v.w, w.x, acc[0][3]);
    acc[1][0] = fmaf(v.x, w.y, acc[1][0]);
    acc[1][1] = fmaf(v.y, w.y, acc[1][1]);
    acc[1][2] = fmaf(v.z, w.y, acc[1][2]);
    acc[1][3] = fmaf(v.w, w.y, acc[1][3]);
    acc[2][0] = fmaf(v.x, w.z, acc[2][0]);
    acc[2][1] = fmaf(v.y, w.z, acc[2][1]);
    acc[2][2] = fmaf(v.z, w.z, acc[2][2]);
    acc[2][3] = fmaf(v.w, w.z, acc[2][3]);
    acc[3][0] = fmaf(v.x, w.w, acc[3][0]);
    acc[3][1] = fmaf(v.y, w.w, acc[3][1]);
    acc[3][2] = fmaf(v.z, w.w, acc[3][2]);
    acc[3][3] = fmaf(v.w, w.w, acc[3][3]);
}

// ---------------------------------------------------------------------------
// K-loop structure: lane = (kr = lane>>4, bq = lane&15). Lane covers batches
// 4bq..4bq+3 at rows k = wave*64 + kr + 4*kk, kk=0..15, processed as two
// 8-deep batches: issue 8 loads (32 VGPRs live), consume, repeat.
// kr reduced by 2 shfl_xor rounds.
// ---------------------------------------------------------------------------

// N nodes sharing one predecessor sp (L2-cached). spv_own = this thread's
// own-column value of sp (valid for tid<128). Publishes to d* when non-null;
// own_out[n] returns the new own-column values (tid<128).
template <int N>
__device__ __forceinline__ void node_group(
    const float* w0l, const float* w1l, const float* w2l,
    const float* __restrict__ sp, float spv_own,
    float* d0, float* d1, float* d2,
    int a0c, int a1c, int a2c,
    float* own_out, int sw, float* red)
{
    const int tid  = threadIdx.x;
    const int lane = tid & 63;
    const int wave = tid >> 6;
    const int bq   = lane & 15;
    const int kr   = lane >> 4;
    const int wb   = __builtin_amdgcn_readfirstlane(wave);

    const float* Wl[3] = {w0l, w1l, w2l};
    float acc[N][4][4];
#pragma unroll
    for (int n = 0; n < N; ++n)
#pragma unroll
        for (int c = 0; c < 4; ++c)
#pragma unroll
            for (int q = 0; q < 4; ++q) acc[n][c][q] = 0.f;

    const int kbase = wb * 64 + kr;
    const float* spq = sp + 4 * bq;

#pragma unroll
    for (int half = 0; half < 2; ++half) {
        float4 v[8];
#pragma unroll
        for (int kk = 0; kk < 8; ++kk)
            v[kk] = ld_v4(spq + (size_t)(kbase + 4 * (half * 8 + kk)) * BB);
#pragma unroll
        for (int kk = 0; kk < 8; ++kk) {
            const int k = kbase + 4 * (half * 8 + kk);
#pragma unroll
            for (int n = 0; n < N; ++n) {
                const float4 w = *(const float4*)(Wl[n] + k * 4);
                fma16(acc[n], v[kk], w);
            }
        }
    }

#pragma unroll
    for (int n = 0; n < N; ++n)
#pragma unroll
        for (int c = 0; c < 4; ++c)
#pragma unroll
            for (int q = 0; q < 4; ++q) {
                float s = acc[n][c][q];
                s += __shfl_xor(s, 16, 64);
                s += __shfl_xor(s, 32, 64);
                acc[n][c][q] = s;
            }
    if (kr == 0) {
#pragma unroll
        for (int n = 0; n < N; ++n)
#pragma unroll
            for (int c = 0; c < 4; ++c) {
                *(float4*)(red + ((wave * N + n) * 4 + c) * 64 + 4 * bq) =
                    make_float4(acc[n][c][0], acc[n][c][1], acc[n][c][2], acc[n][c][3]);
            }
    }
    __syncthreads();

    if (tid < 128) {
        const int j = tid >> 6;
        const int b = tid & 63;
        const int col = sw + j;
        float* dsts[3] = {d0, d1, d2};
        const int acts[3] = {a0c, a1c, a2c};
#pragma unroll
        for (int n = 0; n < N; ++n) {
            float sc = 0.f, sh = 0.f;
#pragma unroll
            for (int w = 0; w < 8; ++w) {
                sc += red[((w * N + n) * 4 + j) * 64 + b];
                sh += red[((w * N + n) * 4 + (j + 2)) * 64 + b];
            }
            const float cg = fsigmoid(sc);
            const float hv = factivate(acts[n], sh);
            const float sv = spv_own + cg * (hv - spv_own);
            if (dsts[n]) st_f1(dsts[n] + col * BB + b, sv);
            own_out[n] = sv;
        }
    }
    __syncthreads();
}

// Two nodes with two different predecessors (L3: node5<-s2, node7<-s3),
// both tanh. s5 published; s7 stays own-column only. Per half: vA[8]+vB[8]
// issued interleaved (64 VGPRs live).
__device__ __forceinline__ void node_pair2(
    const float* wAl, const float* wBl,
    const float* __restrict__ spA, const float* __restrict__ spB,
    float spvA_own, float spvB_own,
    float* dA, float* ownA, float* ownB, int sw, float* red)
{
    const int tid  = threadIdx.x;
    const int lane = tid & 63;
    const int wave = tid >> 6;
    const int bq   = lane & 15;
    const int kr   = lane >> 4;
    const int wb   = __builtin_amdgcn_readfirstlane(wave);

    float accA[4][4], accB[4][4];
#pragma unroll
    for (int c = 0; c < 4; ++c)
#pragma unroll
        for (int q = 0; q < 4; ++q) { accA[c][q] = 0.f; accB[c][q] = 0.f; }

    const int kbase = wb * 64 + kr;
    const float* spAq = spA + 4 * bq;
    const float* spBq = spB + 4 * bq;

#pragma unroll
    for (int half = 0; half < 2; ++half) {
        float4 vA[8], vB[8];
#pragma unroll
        for (int kk = 0; kk < 8; ++kk) {
            const size_t off = (size_t)(kbase + 4 * (half * 8 + kk)) * BB;
            vA[kk] = ld_v4(spAq + off);
            vB[kk] = ld_v4(spBq + off);
        }
#pragma unroll
        for (int kk = 0; kk < 8; ++kk) {
            const int k = kbase + 4 * (half * 8 + kk);
            const float4 wA = *(const float4*)(wAl + k * 4);
            const float4 wB = *(const float4*)(wBl + k * 4);
            fma16(accA, vA[kk], wA);
            fma16(accB, vB[kk], wB);
        }
    }

#pragma unroll
    for (int c = 0; c < 4; ++c)
#pragma unroll
        for (int q = 0; q < 4; ++q) {
            float s = accA[c][q];
            s += __shfl_xor(s, 16, 64);
            s += __shfl_xor(s, 32, 64);
            accA[c][q] = s;
            float u = accB[c][q];
            u += __shfl_xor(u, 16, 64);
            u += __shfl_xor(u, 32, 64);
            accB[c][q] = u;
        }
    if (kr == 0) {
#pragma unroll
        for (int c = 0; c < 4; ++c) {
            *(float4*)(red + ((wave * 2 + 0) * 4 + c) * 64 + 4 * bq) =
                make_float4(accA[c][0], accA[c][1], accA[c][2], accA[c][3]);
            *(float4*)(red + ((wave * 2 + 1) * 4 + c) * 64 + 4 * bq) =
                make_float4(accB[c][0], accB[c][1], accB[c][2], accB[c][3]);
        }
    }
    __syncthreads();

    if (tid < 128) {
        const int j = tid >> 6;
        const int b = tid & 63;
        const int col = sw + j;
        float scA = 0.f, shA = 0.f, scB = 0.f, shB = 0.f;
#pragma unroll
        for (int w = 0; w < 8; ++w) {
            scA += red[((w * 2 + 0) * 4 + j) * 64 + b];
            shA += red[((w * 2 + 0) * 4 + (j + 2)) * 64 + b];
            scB += red[((w * 2 + 1) * 4 + j) * 64 + b];
            shB += red[((w * 2 + 1) * 4 + (j + 2)) * 64 + b];
        }
        const float svA = spvA_own + fsigmoid(scA) * (tanhf(shA) - spvA_own);
        const float svB = spvB_own + fsigmoid(scB) * (tanhf(shB) - spvB_own);
        st_f1(dA + col * BB + b, svA);
        *ownA = svA;
        *ownB = svB;
    }
    __syncthreads();
}

// L0 x-half: x_t @ W0 rows 0..511. Input-only -> runs between barrier
// arrive and wait. Cached loads. Writes red slots 8..15. NO syncthreads.
__device__ __forceinline__ void l0_xpart(
    const float* __restrict__ x, const float* w0l, int t, float* red)
{
    const int tid  = threadIdx.x;
    const int lane = tid & 63;
    const int wave = tid >> 6;
    const int wb   = __builtin_amdgcn_readfirstlane(wave);
    const float* xrow = x + ((size_t)t * BB + lane) * HH + wb * 64;
    float a0 = 0.f, a1 = 0.f, a2 = 0.f, a3 = 0.f;
#pragma unroll 4
    for (int kk = 0; kk < 16; ++kk) {
        const float4 v = *(const float4*)(xrow + 4 * kk);
        const int k = wb * 64 + 4 * kk;
        const float4 w0 = *(const float4*)(w0l + (k + 0) * 4);
        const float4 w1 = *(const float4*)(w0l + (k + 1) * 4);
        const float4 w2 = *(const float4*)(w0l + (k + 2) * 4);
        const float4 w3 = *(const float4*)(w0l + (k + 3) * 4);
        a0 = fmaf(v.x, w0.x, a0); a0 = fmaf(v.y, w1.x, a0);
        a0 = fmaf(v.z, w2.x, a0); a0 = fmaf(v.w, w3.x, a0);
        a1 = fmaf(v.x, w0.y, a1); a1 = fmaf(v.y, w1.y, a1);
        a1 = fmaf(v.z, w2.y, a1); a1 = fmaf(v.w, w3.y, a1);
        a2 = fmaf(v.x, w0.z, a2); a2 = fmaf(v.y, w1.z, a2);
        a2 = fmaf(v.z, w2.z, a2); a2 = fmaf(v.w, w3.z, a2);
        a3 = fmaf(v.x, w0.w, a3); a3 = fmaf(v.y, w1.w, a3);
        a3 = fmaf(v.z, w2.w, a3); a3 = fmaf(v.w, w3.w, a3);
    }
    red[((8 + wave) * 4 + 0) * 64 + lane] = a0;
    red[((8 + wave) * 4 + 1) * 64 + lane] = a1;
    red[((8 + wave) * 4 + 2) * 64 + lane] = a2;
    red[((8 + wave) * 4 + 3) * 64 + lane] = a3;
}

// L0 h-half: h_prev @ W0 rows 512..1023 (slots 0..7), combine with x-half
// (slots 8..15), highway blend. hown = this thread's own-column h (tid<128).
// Returns own-column s0.
__device__ __forceinline__ float l0_hpart(
    const float* w0l, const float* __restrict__ hbuf,
    float* __restrict__ s0, float hown, int sw, float* red)
{
    const int tid  = threadIdx.x;
    const int lane = tid & 63;
    const int wave = tid >> 6;
    const int bq   = lane & 15;
    const int kr   = lane >> 4;
    const int wb   = __builtin_amdgcn_readfirstlane(wave);

    float acc[4][4];
#pragma unroll
    for (int c = 0; c < 4; ++c)
#pragma unroll
        for (int q = 0; q < 4; ++q) acc[c][q] = 0.f;

    const int kbase = wb * 64 + kr;
    const float* hq = hbuf + 4 * bq;

#pragma unroll
    for (int half = 0; half < 2; ++half) {
        float4 v[8];
#pragma unroll
        for (int kk = 0; kk < 8; ++kk)
            v[kk] = ld_v4(hq + (size_t)(kbase + 4 * (half * 8 + kk)) * BB);
#pragma unroll
        for (int kk = 0; kk < 8; ++kk) {
            const int k = kbase + 4 * (half * 8 + kk);
            const float4 w = *(const float4*)(w0l + (k + HH) * 4);
            fma16(acc, v[kk], w);
        }
    }

#pragma unroll
    for (int c = 0; c < 4; ++c)
#pragma unroll
        for (int q = 0; q < 4; ++q) {
            float s = acc[c][q];
            s += __shfl_xor(s, 16, 64);
            s += __shfl_xor(s, 32, 64);
            acc[c][q] = s;
        }
    if (kr == 0) {
#pragma unroll
        for (int c = 0; c < 4; ++c) {
            *(float4*)(red + (wave * 4 + c) * 64 + 4 * bq) =
                make_float4(acc[c][0], acc[c][1], acc[c][2], acc[c][3]);
        }
    }
    __syncthreads();

    float o0 = 0.f;
    if (tid < 128) {
        const int j = tid >> 6;
        const int b = tid & 63;
        const int col = sw + j;
        float sc = 0.f, sh = 0.f;
#pragma unroll
        for (int s = 0; s < 16; ++s) {
            sc += red[(s * 4 + j) * 64 + b];
            sh += red[(s * 4 + (j + 2)) * 64 + b];
        }
        const float c0 = fsigmoid(sc);
        const float h0 = tanhf(sh);
        o0 = hown + c0 * (h0 - hown);
        st_f1(s0 + col * BB + b, o0);
    }
    __syncthreads();
    return o0;
}

__global__ void __launch_bounds__(NTHR, 2) darts_kernel(
    const float* __restrict__ x,    // (T,B,H)
    const float* __restrict__ W0,   // (2H,2H)
    const float* __restrict__ Ws,   // (8,H,2H)
    float* __restrict__ out,        // T*B*H + B*H
    unsigned* __restrict__ bar,
    float* __restrict__ sbuf,       // states [9][H][B]
    float* __restrict__ hbuf)       // h [H][B]
{
    extern __shared__ float wl[];            // 80 KB weights
    __shared__ float red[RED_SLOTS * 256];   // 24 KB reduction buffer
    const int tid = threadIdx.x;
    // XCD-aware swizzle: col-pairs sharing a 64B line -> same XCD.
    const int pair = (blockIdx.x & 7) * 32 + (blockIdx.x >> 3);
    const int sw   = pair * 2;

#define SB(i) (sbuf + (size_t)(i) * HH * BB)

    // One-time: stage this wg's weight columns into LDS (cached loads).
    for (int e = tid; e < NW_ENT; e += NTHR) {
        const float* src;
        if (e < 1024) {
            src = W0 + (size_t)e * C2H;
        } else {
            const int m = (e - 1024) >> 9;
            const int k = (e - 1024) & 511;
            src = Ws + ((size_t)m * HH + k) * C2H;
        }
        const float2 g = *(const float2*)(src + sw);
        const float2 c = *(const float2*)(src + HH + sw);
        wl[e * 4 + 0] = g.x; wl[e * 4 + 1] = g.y;
        wl[e * 4 + 2] = c.x; wl[e * 4 + 3] = c.y;
    }

    // zero-init published h; own-column h carried in a register.
    float hown = 0.f;
    if (tid < 128) {
        const int j = tid >> 6, b = tid & 63;
        st_f1(hbuf + (sw + j) * BB + b, 0.f);
    }
    unsigned g = grid_arrive(bar);
    l0_xpart(x, wl + W0_OFF, 0, red);
    grid_wait(bar, g);

    const float* w0l = wl + W0_OFF;

    for (int t = 0; t < TT; ++t) {
        const float o0 = l0_hpart(w0l, hbuf, SB(0), hown, sw, red);
        grid_barrier(bar);

        // L1: node1 sigmoid, pred s0 -> publish s1
        float o1;
        node_group<1>(wl + WS_OFF(0), nullptr, nullptr, SB(0), o0,
                      SB(1), nullptr, nullptr, 0, 0, 0, &o1, sw, red);
        grid_barrier(bar);

        // L2: nodes 2(relu) 3(relu) 4(identity), pred s1.
        // s2,s3 published (needed by L3); s4 own-column only (mean input).
        float o234[3];
        node_group<3>(wl + WS_OFF(1), wl + WS_OFF(2), wl + WS_OFF(3), SB(1), o1,
                      SB(2), SB(3), nullptr, 1, 1, 3, o234, sw, red);
        grid_barrier(bar);

        // L3: node5 tanh pred s2 -> publish s5 ; node7 tanh pred s3 -> own only
        float o5, o7;
        node_pair2(wl + WS_OFF(4), wl + WS_OFF(6), SB(2), SB(3),
                   o234[0], o234[1], SB(5), &o5, &o7, sw, red);
        grid_barrier(bar);

        // L4: node6 sigmoid + node8 relu, pred s5; own-column only
        float res[2] = {0.f, 0.f};
        node_group<2>(wl + WS_OFF(5), wl + WS_OFF(7), nullptr, SB(5), o5,
                      nullptr, nullptr, nullptr, 0, 1, 0, res, sw, red);

        if (tid < 128) {
            const int j = tid >> 6, b = tid & 63;
            const int col = sw + j;
            float m = o1 + o234[0] + o234[1] + o234[2]
                    + o5 + res[0] + o7 + res[1];
            m *= 0.125f;
            hown = m;
            st_f1(hbuf + col * BB + b, m);                       // coherent publish
            __builtin_nontemporal_store(m, &out[((size_t)t * BB + b) * HH + col]);
            if (t == TT - 1) {
                __builtin_nontemporal_store(
                    m, &out[(size_t)TT * BB * HH + (size_t)b * HH + col]);
            }
        }
        // final barrier; next step's x-part hides under the wait.
        g = grid_arrive(bar);
        if (t + 1 < TT) l0_xpart(x, w0l, t + 1, red);
        grid_wait(bar, g);
    }
#undef SB
}

extern "C" void kernel_launch(void* const* d_in, const int* in_sizes, int n_in,
                              void* d_out, int out_size, void* d_ws, size_t ws_size,
                              hipStream_t stream) {
    const float* x  = (const float*)d_in[0];
    const float* W0 = (const float*)d_in[1];
    const float* Ws = (const float*)d_in[2];
    float* out = (float*)d_out;

    unsigned char* ws = (unsigned char*)d_ws;
    unsigned* bar = (unsigned*)ws;                          // 1 KB barrier
    float* sbuf = (float*)(ws + 1024);                      // 9*H*B*4 = 1.18 MB
    float* hbuf = (float*)(ws + 1024 + 9 * HH * BB * 4);    // 128 KB

    hipMemsetAsync(bar, 0, 1024, stream);

    void* args[] = {(void*)&x, (void*)&W0, (void*)&Ws, (void*)&out,
                    (void*)&bar, (void*)&sbuf, (void*)&hbuf};
    hipLaunchCooperativeKernel((const void*)darts_kernel, dim3(NBLK), dim3(NTHR),
                               args, (NW_ENT * 4 * sizeof(float)), stream);
}

// Round 7
// 34465.472 us; speedup vs baseline: 1.2179x; 1.2179x over previous
//
#include <hip/hip_runtime.h>
#include <stdint.h>
#include <stddef.h>

// DARTS RNN cell, MI355X. Round 9: 16B coherent state loads (halve LLC
// request count), rebased on the round-7 build (38.9ms).
//
// Round-8 post-mortem: cached loads + per-barrier acquire fence REGRESSED
// (42ms) - the buffer_inv wipes L2 exactly when all wgs issue their phase
// loads, so no dedup, plus inv cost. Reverted.
//
// Refined budget at 38us/step: VALU ~7us, barriers ~7-10us, remainder
// ~15-20us = LLC REQUEST RATE: state loads are 8B packets (64-bit atomic
// pairs), ~28M requests/step to the memory-side Infinity Cache. This
// round: one change - each 16B state read is a single inline-asm
// global_load_dwordx4 sc0 sc1 (L1/L2-bypassing, served by the coherent
// MALL). Same bytes, HALF the requests. Manual vmcnt: issue the depth-8
// batch, s_waitcnt vmcnt(0), sched_barrier(0), consume.
//
// Carried from round 7: relaxed monotonic hierarchical barrier, depth-8
// two-stage K-loop preload, own-column values in registers, x-part
// overlapped under the final barrier wait, nontemporal out stores.
//
// Partition: 256 wgs x 512 thr; wg owns 2 state columns; weights in LDS
// (80 KB). 5 grid barriers per timestep.

#define TT 1024
#define BB 64
#define HH 512
#define C2H 1024
#define NBLK 256
#define NTHR 512

#define NW_ENT 5120
#define W0_OFF 0
#define WS_OFF(m) (4096 + (m) * 2048)

#define RED_SLOTS 24

#define SCOPE __HIP_MEMORY_SCOPE_AGENT

// ---- coherent state movement ----
// 16B LLC-coherent load: bypasses L1+L2 (sc0 sc1), served by the
// memory-side Infinity Cache. Caller must WAITVM() before consuming.
#define LD16(dst, ptr) \
    asm volatile("global_load_dwordx4 %0, %1, off sc0 sc1" \
                 : "=v"(dst) : "v"(ptr))

// Drain all outstanding loads, then fence the scheduler so consuming FMAs
// are not hoisted above the waitcnt (guide rule #18).
#define WAITVM() do { \
    asm volatile("s_waitcnt vmcnt(0)" ::: "memory"); \
    __builtin_amdgcn_sched_barrier(0); \
} while (0)

// 4B coherent store (write-through to LLC), as before.
__device__ __forceinline__ void st_f1(float* p, float v) {
    union { float f; unsigned u; } c; c.f = v;
    __hip_atomic_store((unsigned*)p, c.u, __ATOMIC_RELAXED, SCOPE);
}

// ---- grid barrier: hierarchical, monotonic, fully relaxed ----
// bar layout (unsigned): leaf i at bar[16*i] (i<8), root at bar[128],
// gen at bar[144]. Counters never reset; (a&31)==31 / (r&7)==7 arm the
// next stage. 5*1024 barriers << 2^32/32, no overflow.
__device__ __forceinline__ unsigned grid_arrive(unsigned* bar) {
    __syncthreads();   // drains this wg's stores (vmcnt 0) in every wave
    unsigned g = 0;
    if (threadIdx.x == 0) {
        unsigned* leaf = bar + 16 * (blockIdx.x & 7);
        unsigned* root = bar + 128;
        unsigned* gen  = bar + 144;
        g = __hip_atomic_load(gen, __ATOMIC_RELAXED, SCOPE);
        unsigned a = __hip_atomic_fetch_add(leaf, 1u, __ATOMIC_RELAXED, SCOPE);
        if ((a & 31u) == 31u) {
            unsigned r = __hip_atomic_fetch_add(root, 1u, __ATOMIC_RELAXED, SCOPE);
            if ((r & 7u) == 7u) {
                __hip_atomic_fetch_add(gen, 1u, __ATOMIC_RELAXED, SCOPE);
            }
        }
    }
    return g;
}

__device__ __forceinline__ void grid_wait(unsigned* bar, unsigned g) {
    if (threadIdx.x == 0) {
        unsigned* gen = bar + 144;
        while (__hip_atomic_load(gen, __ATOMIC_RELAXED, SCOPE) == g) {
            __builtin_amdgcn_s_sleep(2);
        }
    }
    __syncthreads();
}

__device__ __forceinline__ void grid_barrier(unsigned* bar) {
    unsigned g = grid_arrive(bar);
    grid_wait(bar, g);
}

__device__ __forceinline__ float fsigmoid(float v) {
    return 1.f / (1.f + __expf(-v));
}

// act codes: 0=sigmoid 1=relu 2=tanh 3=identity
__device__ __forceinline__ float factivate(int a, float v) {
    if (a == 0) return fsigmoid(v);
    if (a == 1) return fmaxf(v, 0.f);
    if (a == 2) return tanhf(v);
    return v;
}

// 16 FMAs: acc[c][q] += v[q] * w[c]
__device__ __forceinline__ void fma16(float (&acc)[4][4], const float4 v, const float4 w) {
    acc[0][0] = fmaf(v.x, w.x, acc[0][0]);
    acc[0][1] = fmaf(v.y, w.x, acc[0][1]);
    acc[0][2] = fmaf(v.z, w.x, acc[0][2]);
    acc[0][3] = fmaf(v.w, w.x, acc[0][3]);
    acc[1][0] = fmaf(v.x, w.y, acc[1][0]);
    acc[1][1] = fmaf(v.y, w.y, acc[1][1]);
    acc[1][2] = fmaf(v.z, w.y, acc[1][2]);
    acc[1][3] = fmaf(v.w, w.y, acc[1][3]);
    acc[2][0] = fmaf(v.x, w.z, acc[2][0]);
    acc[2][1] = fmaf(v.y, w.z, acc[2][1]);
    acc[2][2] = fmaf(v.z, w.z, acc[2][2]);
    acc[2][3] = fmaf(v.w, w.z, acc[2][3]);
    acc[3][0] = fmaf(v.x, w.w, acc[3][0]);
    acc[3][1] = fmaf(v.y, w.w, acc[3][1]);
    acc[3][2] = fmaf(v.z, w.w, acc[3][2]);
    acc[3][3] = fmaf(v.w, w.w, acc[3][3]);
}

// ---------------------------------------------------------------------------
// K-loop structure: lane = (kr = lane>>4, bq = lane&15). Lane covers batches
// 4bq..4bq+3 at rows k = wave*64 + kr + 4*kk, kk=0..15, processed as two
// 8-deep batches: issue 8 16B coherent loads, vmcnt(0), consume, repeat.
// kr reduced by 2 shfl_xor rounds.
// ---------------------------------------------------------------------------

// N nodes sharing one predecessor sp (LLC). spv_own = this thread's
// own-column value of sp (valid for tid<128). Publishes to d* when non-null;
// own_out[n] returns the new own-column values (tid<128).
template <int N>
__device__ __forceinline__ void node_group(
    const float* w0l, const float* w1l, const float* w2l,
    const float* __restrict__ sp, float spv_own,
    float* d0, float* d1, float* d2,
    int a0c, int a1c, int a2c,
    float* own_out, int sw, float* red)
{
    const int tid  = threadIdx.x;
    const int lane = tid & 63;
    const int wave = tid >> 6;
    const int bq   = lane & 15;
    const int kr   = lane >> 4;
    const int wb   = __builtin_amdgcn_readfirstlane(wave);

    const float* Wl[3] = {w0l, w1l, w2l};
    float acc[N][4][4];
#pragma unroll
    for (int n = 0; n < N; ++n)
#pragma unroll
        for (int c = 0; c < 4; ++c)
#pragma unroll
            for (int q = 0; q < 4; ++q) acc[n][c][q] = 0.f;

    const int kbase = wb * 64 + kr;
    const float* spq = sp + 4 * bq;

#pragma unroll
    for (int half = 0; half < 2; ++half) {
        float4 v[8];
#pragma unroll
        for (int kk = 0; kk < 8; ++kk)
            LD16(v[kk], spq + (size_t)(kbase + 4 * (half * 8 + kk)) * BB);
        WAITVM();
#pragma unroll
        for (int kk = 0; kk < 8; ++kk) {
            const int k = kbase + 4 * (half * 8 + kk);
#pragma unroll
            for (int n = 0; n < N; ++n) {
                const float4 w = *(const float4*)(Wl[n] + k * 4);
                fma16(acc[n], v[kk], w);
            }
        }
    }

#pragma unroll
    for (int n = 0; n < N; ++n)
#pragma unroll
        for (int c = 0; c < 4; ++c)
#pragma unroll
            for (int q = 0; q < 4; ++q) {
                float s = acc[n][c][q];
                s += __shfl_xor(s, 16, 64);
                s += __shfl_xor(s, 32, 64);
                acc[n][c][q] = s;
            }
    if (kr == 0) {
#pragma unroll
        for (int n = 0; n < N; ++n)
#pragma unroll
            for (int c = 0; c < 4; ++c) {
                *(float4*)(red + ((wave * N + n) * 4 + c) * 64 + 4 * bq) =
                    make_float4(acc[n][c][0], acc[n][c][1], acc[n][c][2], acc[n][c][3]);
            }
    }
    __syncthreads();

    if (tid < 128) {
        const int j = tid >> 6;
        const int b = tid & 63;
        const int col = sw + j;
        float* dsts[3] = {d0, d1, d2};
        const int acts[3] = {a0c, a1c, a2c};
#pragma unroll
        for (int n = 0; n < N; ++n) {
            float sc = 0.f, sh = 0.f;
#pragma unroll
            for (int w = 0; w < 8; ++w) {
                sc += red[((w * N + n) * 4 + j) * 64 + b];
                sh += red[((w * N + n) * 4 + (j + 2)) * 64 + b];
            }
            const float cg = fsigmoid(sc);
            const float hv = factivate(acts[n], sh);
            const float sv = spv_own + cg * (hv - spv_own);
            if (dsts[n]) st_f1(dsts[n] + col * BB + b, sv);
            own_out[n] = sv;
        }
    }
    __syncthreads();
}

// Two nodes with two different predecessors (L3: node5<-s2, node7<-s3),
// both tanh. s5 published; s7 stays own-column only. Per half: vA[8]+vB[8]
// issued together (16 loads in flight), one vmcnt drain.
__device__ __forceinline__ void node_pair2(
    const float* wAl, const float* wBl,
    const float* __restrict__ spA, const float* __restrict__ spB,
    float spvA_own, float spvB_own,
    float* dA, float* ownA, float* ownB, int sw, float* red)
{
    const int tid  = threadIdx.x;
    const int lane = tid & 63;
    const int wave = tid >> 6;
    const int bq   = lane & 15;
    const int kr   = lane >> 4;
    const int wb   = __builtin_amdgcn_readfirstlane(wave);

    float accA[4][4], accB[4][4];
#pragma unroll
    for (int c = 0; c < 4; ++c)
#pragma unroll
        for (int q = 0; q < 4; ++q) { accA[c][q] = 0.f; accB[c][q] = 0.f; }

    const int kbase = wb * 64 + kr;
    const float* spAq = spA + 4 * bq;
    const float* spBq = spB + 4 * bq;

#pragma unroll
    for (int half = 0; half < 2; ++half) {
        float4 vA[8], vB[8];
#pragma unroll
        for (int kk = 0; kk < 8; ++kk) {
            const size_t off = (size_t)(kbase + 4 * (half * 8 + kk)) * BB;
            LD16(vA[kk], spAq + off);
            LD16(vB[kk], spBq + off);
        }
        WAITVM();
#pragma unroll
        for (int kk = 0; kk < 8; ++kk) {
            const int k = kbase + 4 * (half * 8 + kk);
            const float4 wA = *(const float4*)(wAl + k * 4);
            const float4 wB = *(const float4*)(wBl + k * 4);
            fma16(accA, vA[kk], wA);
            fma16(accB, vB[kk], wB);
        }
    }

#pragma unroll
    for (int c = 0; c < 4; ++c)
#pragma unroll
        for (int q = 0; q < 4; ++q) {
            float s = accA[c][q];
            s += __shfl_xor(s, 16, 64);
            s += __shfl_xor(s, 32, 64);
            accA[c][q] = s;
            float u = accB[c][q];
            u += __shfl_xor(u, 16, 64);
            u += __shfl_xor(u, 32, 64);
            accB[c][q] = u;
        }
    if (kr == 0) {
#pragma unroll
        for (int c = 0; c < 4; ++c) {
            *(float4*)(red + ((wave * 2 + 0) * 4 + c) * 64 + 4 * bq) =
                make_float4(accA[c][0], accA[c][1], accA[c][2], accA[c][3]);
            *(float4*)(red + ((wave * 2 + 1) * 4 + c) * 64 + 4 * bq) =
                make_float4(accB[c][0], accB[c][1], accB[c][2], accB[c][3]);
        }
    }
    __syncthreads();

    if (tid < 128) {
        const int j = tid >> 6;
        const int b = tid & 63;
        const int col = sw + j;
        float scA = 0.f, shA = 0.f, scB = 0.f, shB = 0.f;
#pragma unroll
        for (int w = 0; w < 8; ++w) {
            scA += red[((w * 2 + 0) * 4 + j) * 64 + b];
            shA += red[((w * 2 + 0) * 4 + (j + 2)) * 64 + b];
            scB += red[((w * 2 + 1) * 4 + j) * 64 + b];
            shB += red[((w * 2 + 1) * 4 + (j + 2)) * 64 + b];
        }
        const float svA = spvA_own + fsigmoid(scA) * (tanhf(shA) - spvA_own);
        const float svB = spvB_own + fsigmoid(scB) * (tanhf(shB) - spvB_own);
        st_f1(dA + col * BB + b, svA);
        *ownA = svA;
        *ownB = svB;
    }
    __syncthreads();
}

// L0 x-half: x_t @ W0 rows 0..511. Input-only -> runs between barrier
// arrive and wait. Normal cached loads (x is read-only). Writes red slots
// 8..15. NO syncthreads here.
__device__ __forceinline__ void l0_xpart(
    const float* __restrict__ x, const float* w0l, int t, float* red)
{
    const int tid  = threadIdx.x;
    const int lane = tid & 63;
    const int wave = tid >> 6;
    const int wb   = __builtin_amdgcn_readfirstlane(wave);
    const float* xrow = x + ((size_t)t * BB + lane) * HH + wb * 64;
    float a0 = 0.f, a1 = 0.f, a2 = 0.f, a3 = 0.f;
#pragma unroll 4
    for (int kk = 0; kk < 16; ++kk) {
        const float4 v = *(const float4*)(xrow + 4 * kk);
        const int k = wb * 64 + 4 * kk;
        const float4 w0 = *(const float4*)(w0l + (k + 0) * 4);
        const float4 w1 = *(const float4*)(w0l + (k + 1) * 4);
        const float4 w2 = *(const float4*)(w0l + (k + 2) * 4);
        const float4 w3 = *(const float4*)(w0l + (k + 3) * 4);
        a0 = fmaf(v.x, w0.x, a0); a0 = fmaf(v.y, w1.x, a0);
        a0 = fmaf(v.z, w2.x, a0); a0 = fmaf(v.w, w3.x, a0);
        a1 = fmaf(v.x, w0.y, a1); a1 = fmaf(v.y, w1.y, a1);
        a1 = fmaf(v.z, w2.y, a1); a1 = fmaf(v.w, w3.y, a1);
        a2 = fmaf(v.x, w0.z, a2); a2 = fmaf(v.y, w1.z, a2);
        a2 = fmaf(v.z, w2.z, a2); a2 = fmaf(v.w, w3.z, a2);
        a3 = fmaf(v.x, w0.w, a3); a3 = fmaf(v.y, w1.w, a3);
        a3 = fmaf(v.z, w2.w, a3); a3 = fmaf(v.w, w3.w, a3);
    }
    red[((8 + wave) * 4 + 0) * 64 + lane] = a0;
    red[((8 + wave) * 4 + 1) * 64 + lane] = a1;
    red[((8 + wave) * 4 + 2) * 64 + lane] = a2;
    red[((8 + wave) * 4 + 3) * 64 + lane] = a3;
}

// L0 h-half: h_prev @ W0 rows 512..1023 (slots 0..7), combine with x-half
// (slots 8..15), highway blend. hown = this thread's own-column h (tid<128).
// Returns own-column s0.
__device__ __forceinline__ float l0_hpart(
    const float* w0l, const float* __restrict__ hbuf,
    float* __restrict__ s0, float hown, int sw, float* red)
{
    const int tid  = threadIdx.x;
    const int lane = tid & 63;
    const int wave = tid >> 6;
    const int bq   = lane & 15;
    const int kr   = lane >> 4;
    const int wb   = __builtin_amdgcn_readfirstlane(wave);

    float acc[4][4];
#pragma unroll
    for (int c = 0; c < 4; ++c)
#pragma unroll
        for (int q = 0; q < 4; ++q) acc[c][q] = 0.f;

    const int kbase = wb * 64 + kr;
    const float* hq = hbuf + 4 * bq;

#pragma unroll
    for (int half = 0; half < 2; ++half) {
        float4 v[8];
#pragma unroll
        for (int kk = 0; kk < 8; ++kk)
            LD16(v[kk], hq + (size_t)(kbase + 4 * (half * 8 + kk)) * BB);
        WAITVM();
#pragma unroll
        for (int kk = 0; kk < 8; ++kk) {
            const int k = kbase + 4 * (half * 8 + kk);
            const float4 w = *(const float4*)(w0l + (k + HH) * 4);
            fma16(acc, v[kk], w);
        }
    }

#pragma unroll
    for (int c = 0; c < 4; ++c)
#pragma unroll
        for (int q = 0; q < 4; ++q) {
            float s = acc[c][q];
            s += __shfl_xor(s, 16, 64);
            s += __shfl_xor(s, 32, 64);
            acc[c][q] = s;
        }
    if (kr == 0) {
#pragma unroll
        for (int c = 0; c < 4; ++c) {
            *(float4*)(red + (wave * 4 + c) * 64 + 4 * bq) =
                make_float4(acc[c][0], acc[c][1], acc[c][2], acc[c][3]);
        }
    }
    __syncthreads();

    float o0 = 0.f;
    if (tid < 128) {
        const int j = tid >> 6;
        const int b = tid & 63;
        const int col = sw + j;
        float sc = 0.f, sh = 0.f;
#pragma unroll
        for (int s = 0; s < 16; ++s) {
            sc += red[(s * 4 + j) * 64 + b];
            sh += red[(s * 4 + (j + 2)) * 64 + b];
        }
        const float c0 = fsigmoid(sc);
        const float h0 = tanhf(sh);
        o0 = hown + c0 * (h0 - hown);
        st_f1(s0 + col * BB + b, o0);
    }
    __syncthreads();
    return o0;
}

__global__ void __launch_bounds__(NTHR, 2) darts_kernel(
    const float* __restrict__ x,    // (T,B,H)
    const float* __restrict__ W0,   // (2H,2H)
    const float* __restrict__ Ws,   // (8,H,2H)
    float* __restrict__ out,        // T*B*H + B*H
    unsigned* __restrict__ bar,
    float* __restrict__ sbuf,       // states [9][H][B]
    float* __restrict__ hbuf)       // h [H][B]
{
    extern __shared__ float wl[];            // 80 KB weights
    __shared__ float red[RED_SLOTS * 256];   // 24 KB reduction buffer
    const int tid = threadIdx.x;
    // XCD-aware swizzle: col-pairs sharing a 64B line -> same XCD.
    const int pair = (blockIdx.x & 7) * 32 + (blockIdx.x >> 3);
    const int sw   = pair * 2;

#define SB(i) (sbuf + (size_t)(i) * HH * BB)

    // One-time: stage this wg's weight columns into LDS (cached loads).
    for (int e = tid; e < NW_ENT; e += NTHR) {
        const float* src;
        if (e < 1024) {
            src = W0 + (size_t)e * C2H;
        } else {
            const int m = (e - 1024) >> 9;
            const int k = (e - 1024) & 511;
            src = Ws + ((size_t)m * HH + k) * C2H;
        }
        const float2 g = *(const float2*)(src + sw);
        const float2 c = *(const float2*)(src + HH + sw);
        wl[e * 4 + 0] = g.x; wl[e * 4 + 1] = g.y;
        wl[e * 4 + 2] = c.x; wl[e * 4 + 3] = c.y;
    }

    // zero-init published h; own-column h carried in a register.
    float hown = 0.f;
    if (tid < 128) {
        const int j = tid >> 6, b = tid & 63;
        st_f1(hbuf + (sw + j) * BB + b, 0.f);
    }
    unsigned g = grid_arrive(bar);
    l0_xpart(x, wl + W0_OFF, 0, red);
    grid_wait(bar, g);

    const float* w0l = wl + W0_OFF;

    for (int t = 0; t < TT; ++t) {
        const float o0 = l0_hpart(w0l, hbuf, SB(0), hown, sw, red);
        grid_barrier(bar);

        // L1: node1 sigmoid, pred s0 -> publish s1
        float o1;
        node_group<1>(wl + WS_OFF(0), nullptr, nullptr, SB(0), o0,
                      SB(1), nullptr, nullptr, 0, 0, 0, &o1, sw, red);
        grid_barrier(bar);

        // L2: nodes 2(relu) 3(relu) 4(identity), pred s1.
        // s2,s3 published (needed by L3); s4 own-column only (mean input).
        float o234[3];
        node_group<3>(wl + WS_OFF(1), wl + WS_OFF(2), wl + WS_OFF(3), SB(1), o1,
                      SB(2), SB(3), nullptr, 1, 1, 3, o234, sw, red);
        grid_barrier(bar);

        // L3: node5 tanh pred s2 -> publish s5 ; node7 tanh pred s3 -> own only
        float o5, o7;
        node_pair2(wl + WS_OFF(4), wl + WS_OFF(6), SB(2), SB(3),
                   o234[0], o234[1], SB(5), &o5, &o7, sw, red);
        grid_barrier(bar);

        // L4: node6 sigmoid + node8 relu, pred s5; own-column only
        float res[2] = {0.f, 0.f};
        node_group<2>(wl + WS_OFF(5), wl + WS_OFF(7), nullptr, SB(5), o5,
                      nullptr, nullptr, nullptr, 0, 1, 0, res, sw, red);

        if (tid < 128) {
            const int j = tid >> 6, b = tid & 63;
            const int col = sw + j;
            float m = o1 + o234[0] + o234[1] + o234[2]
                    + o5 + res[0] + o7 + res[1];
            m *= 0.125f;
            hown = m;
            st_f1(hbuf + col * BB + b, m);                       // coherent publish
            __builtin_nontemporal_store(m, &out[((size_t)t * BB + b) * HH + col]);
            if (t == TT - 1) {
                __builtin_nontemporal_store(
                    m, &out[(size_t)TT * BB * HH + (size_t)b * HH + col]);
            }
        }
        // final barrier; next step's x-part hides under the wait.
        g = grid_arrive(bar);
        if (t + 1 < TT) l0_xpart(x, w0l, t + 1, red);
        grid_wait(bar, g);
    }
#undef SB
}

extern "C" void kernel_launch(void* const* d_in, const int* in_sizes, int n_in,
                              void* d_out, int out_size, void* d_ws, size_t ws_size,
                              hipStream_t stream) {
    const float* x  = (const float*)d_in[0];
    const float* W0 = (const float*)d_in[1];
    const float* Ws = (const float*)d_in[2];
    float* out = (float*)d_out;

    unsigned char* ws = (unsigned char*)d_ws;
    unsigned* bar = (unsigned*)ws;                          // 1 KB barrier
    float* sbuf = (float*)(ws + 1024);                      // 9*H*B*4 = 1.18 MB
    float* hbuf = (float*)(ws + 1024 + 9 * HH * BB * 4);    // 128 KB

    hipMemsetAsync(bar, 0, 1024, stream);

    void* args[] = {(void*)&x, (void*)&W0, (void*)&Ws, (void*)&out,
                    (void*)&bar, (void*)&sbuf, (void*)&hbuf};
    hipLaunchCooperativeKernel((const void*)darts_kernel, dim3(NBLK), dim3(NTHR),
                               args, (NW_ENT * 4 * sizeof(float)), stream);
}